// Round 3
// baseline (163.815 us; speedup 1.0000x reference)
//
#include <hip/hip_runtime.h>

#define BATCH 4
#define NPTS 16384
#define MPTS 16384
#define NH 32
#define NK 15
#define NF 64
#define NC 64
#define MT 16

typedef short short8 __attribute__((ext_vector_type(8)));
typedef float floatx4 __attribute__((ext_vector_type(4)));

__device__ __forceinline__ unsigned short f2bf(float x) {
    unsigned int u = __builtin_bit_cast(unsigned int, x);
    u = u + 0x7FFFu + ((u >> 16) & 1u);   // RNE
    return (unsigned short)(u >> 16);
}

// pack two floats -> bf16x2 dword by truncation (1 v_perm)
__device__ __forceinline__ unsigned pack_trunc(float lo, float hi) {
    return __builtin_amdgcn_perm(__builtin_bit_cast(unsigned, hi),
                                 __builtin_bit_cast(unsigned, lo), 0x07060302u);
}

// ---------- prep 1: features fp32 -> bf16 (ws) ----------
__global__ void feat_cvt_kernel(const float* __restrict__ src, unsigned short* __restrict__ dst) {
    const int gid = blockIdx.x * 256 + threadIdx.x;        // 524288 threads x 8 elems
    const size_t base = (size_t)gid * 8;
    float4 a = *(const float4*)(src + base);
    float4 b = *(const float4*)(src + base + 4);
    uint4 o;
    o.x = (unsigned)f2bf(a.x) | ((unsigned)f2bf(a.y) << 16);
    o.y = (unsigned)f2bf(a.z) | ((unsigned)f2bf(a.w) << 16);
    o.z = (unsigned)f2bf(b.x) | ((unsigned)f2bf(b.y) << 16);
    o.w = (unsigned)f2bf(b.z) | ((unsigned)f2bf(b.w) << 16);
    *(uint4*)(dst + base) = o;
}

// ---------- prep 2: k_values -> bf16 in einsum2 B-fragment order ----------
// kappa = f*16 + k (k padded to 16, zero for k==15). KF = 1024 -> 32 mfma steps.
__global__ void vprep_kernel(const float* __restrict__ kv, unsigned short* __restrict__ vp) {
    const int gid = blockIdx.x * 256 + threadIdx.x;        // 8192 threads
    const int lane = gid & 63;
    const int ct   = (gid >> 6) & 3;
    const int kk   = gid >> 8;                             // 0..31
    const int c    = ct * 16 + (lane & 15);
    const int kap0 = kk * 32 + (lane >> 4) * 8;
    unsigned int o[4];
    #pragma unroll
    for (int jj = 0; jj < 4; jj++) {
        unsigned short lo, hi;
        {
            const int kap = kap0 + jj * 2;
            const int f = kap >> 4, k = kap & 15;
            lo = (k < NK) ? f2bf(kv[((size_t)(k * NF + f)) * NC + c]) : (unsigned short)0;
        }
        {
            const int kap = kap0 + jj * 2 + 1;
            const int f = kap >> 4, k = kap & 15;
            hi = (k < NK) ? f2bf(kv[((size_t)(k * NF + f)) * NC + c]) : (unsigned short)0;
        }
        o[jj] = (unsigned)lo | ((unsigned)hi << 16);
    }
    *(uint4*)(vp + (size_t)gid * 8) = make_uint4(o[0], o[1], o[2], o[3]);
}

// ---------- main kernel ----------
__global__ __launch_bounds__(256, 3) void kpconv_kernel(
    const float* __restrict__ points,          // [B,N,3]
    const unsigned short* __restrict__ featbf, // [B,N,F] bf16 (ws)
    const float* __restrict__ outpts,          // [B,M,3]
    const float* __restrict__ kpts,            // [K,3]
    const unsigned short* __restrict__ vp,     // einsum2 B-frag-ordered V bf16 (ws)
    const int*   __restrict__ nbr,             // [B,M,H]
    float* __restrict__ out)                   // [B,M,C]
{
    __shared__ unsigned short awf[32 * 512];   // wf in A-frag order: [kk][chunk(swizzled)][8]  32768 B
    __shared__ unsigned short feat_s[4 * 1288];// [pl][f<32][h pad40], pl-stride 1288 shorts    10304 B
    __shared__ float4 rel_s[4 * 32];           // [pl][h] rel coords                             2048 B
    __shared__ int   idx_s[512];               //                                                2048 B
    __shared__ float opt_s[48];
    __shared__ float kp_s[48];

    const int tid   = threadIdx.x;
    const int batch = blockIdx.x >> 10;
    const int m0    = (blockIdx.x & 1023) << 4;

    if (tid < 48) kp_s[tid] = (tid < 45) ? kpts[tid] : 1e9f;   // sentinel -> w=0 for k=15
    if (tid >= 64 && tid < 112)
        opt_s[tid - 64] = outpts[(size_t)(batch * MPTS + m0) * 3 + (tid - 64)];
    {
        const size_t nb = (size_t)(batch * MPTS + m0) * NH;
        idx_s[tid]       = nbr[nb + tid];
        idx_s[256 + tid] = nbr[nb + 256 + tid];
    }
    __syncthreads();

    const int g    = tid >> 6;    // wave id
    const int lane = tid & 63;
    const int cl   = lane & 15;
    const int q    = lane >> 4;

    for (int r = 0; r < 4; r++) {
        // per-round staging addresses (shared by both halves)
        const int spl = tid >> 6;
        const int sa  = tid & 15;           // h-pair
        const int sfc = (tid >> 4) & 3;     // f-chunk of 8
        const int srow = (r * 4 + spl) * 32 + sa * 2;
        const int id0 = idx_s[srow], id1 = idx_s[srow + 1];
        const unsigned short* s0p = featbf + ((size_t)(batch * NPTS) + id0) * NF + sfc * 8;
        const unsigned short* s1p = featbf + ((size_t)(batch * NPTS) + id1) * NF + sfc * 8;
        unsigned short* dp = &feat_s[spl * 1288 + (sfc * 8) * 40 + sa * 2];

        // ---- S0: stage feat half 0 ([f][h] h-pair packed) + rel coords ----
        {
            uint4 ra = *(const uint4*)s0p;
            uint4 rb = *(const uint4*)s1p;
            *(unsigned*)(dp + 0 * 40) = __builtin_amdgcn_perm(rb.x, ra.x, 0x05040100u);
            *(unsigned*)(dp + 1 * 40) = __builtin_amdgcn_perm(rb.x, ra.x, 0x07060302u);
            *(unsigned*)(dp + 2 * 40) = __builtin_amdgcn_perm(rb.y, ra.y, 0x05040100u);
            *(unsigned*)(dp + 3 * 40) = __builtin_amdgcn_perm(rb.y, ra.y, 0x07060302u);
            *(unsigned*)(dp + 4 * 40) = __builtin_amdgcn_perm(rb.z, ra.z, 0x05040100u);
            *(unsigned*)(dp + 5 * 40) = __builtin_amdgcn_perm(rb.z, ra.z, 0x07060302u);
            *(unsigned*)(dp + 6 * 40) = __builtin_amdgcn_perm(rb.w, ra.w, 0x05040100u);
            *(unsigned*)(dp + 7 * 40) = __builtin_amdgcn_perm(rb.w, ra.w, 0x07060302u);
        }
        if (tid < 128) {
            const int rpl = tid >> 5, rh = tid & 31;
            const int rid = idx_s[(r * 4 + rpl) * 32 + rh];
            const float* pp = points + ((size_t)(batch * NPTS) + rid) * 3;
            const int p = r * 4 + rpl;
            rel_s[rpl * 32 + rh] = make_float4(pp[0] - opt_s[p * 3 + 0],
                                               pp[1] - opt_s[p * 3 + 1],
                                               pp[2] - opt_s[p * 3 + 2], 0.f);
        }
        __syncthreads();

        // ---- E1: w A-frag (registers) + einsum1 tiles 0,1 ----
        const int p = r * 4 + g;
        short8 af;
        {
            const float kx = kp_s[cl * 3 + 0];
            const float ky = kp_s[cl * 3 + 1];
            const float kz = kp_s[cl * 3 + 2];
            float wv[8];
            #pragma unroll
            for (int j = 0; j < 8; j++) {
                const float4 rr = rel_s[g * 32 + q * 8 + j];
                const float dx = rr.x - kx, dy = rr.y - ky, dz = rr.z - kz;
                const float d = sqrtf(dx * dx + dy * dy + dz * dz);
                wv[j] = fmaxf(1.f - d, 0.f);            // EXTENT = 1.0; cl==15 -> 0
            }
            uint4 ua;
            ua.x = pack_trunc(wv[0], wv[1]);
            ua.y = pack_trunc(wv[2], wv[3]);
            ua.z = pack_trunc(wv[4], wv[5]);
            ua.w = pack_trunc(wv[6], wv[7]);
            af = __builtin_bit_cast(short8, ua);
        }
        #pragma unroll
        for (int t = 0; t < 2; t++) {
            const uint4 ub = *(const uint4*)&feat_s[g * 1288 + (t * 16 + cl) * 40 + q * 8];
            floatx4 dd = {0.f, 0.f, 0.f, 0.f};
            dd = __builtin_amdgcn_mfma_f32_16x16x32_bf16(af, __builtin_bit_cast(short8, ub), dd, 0, 0, 0);
            const int kk    = 8 * t + (cl >> 1);
            const int q2    = (2 * cl + (q >> 1)) & 3;
            const int chunk = (p ^ (kk & 15)) | (q2 << 4);
            unsigned* wp = (unsigned*)awf + kk * 256 + chunk * 4 + (q & 1) * 2;
            wp[0] = pack_trunc(dd[0], dd[1]);
            wp[1] = pack_trunc(dd[2], dd[3]);
        }
        __syncthreads();

        // ---- S1: stage feat half 1 ----
        {
            uint4 ra = *(const uint4*)(s0p + 32);
            uint4 rb = *(const uint4*)(s1p + 32);
            *(unsigned*)(dp + 0 * 40) = __builtin_amdgcn_perm(rb.x, ra.x, 0x05040100u);
            *(unsigned*)(dp + 1 * 40) = __builtin_amdgcn_perm(rb.x, ra.x, 0x07060302u);
            *(unsigned*)(dp + 2 * 40) = __builtin_amdgcn_perm(rb.y, ra.y, 0x05040100u);
            *(unsigned*)(dp + 3 * 40) = __builtin_amdgcn_perm(rb.y, ra.y, 0x07060302u);
            *(unsigned*)(dp + 4 * 40) = __builtin_amdgcn_perm(rb.z, ra.z, 0x05040100u);
            *(unsigned*)(dp + 5 * 40) = __builtin_amdgcn_perm(rb.z, ra.z, 0x07060302u);
            *(unsigned*)(dp + 6 * 40) = __builtin_amdgcn_perm(rb.w, ra.w, 0x05040100u);
            *(unsigned*)(dp + 7 * 40) = __builtin_amdgcn_perm(rb.w, ra.w, 0x07060302u);
        }
        __syncthreads();

        // ---- E2: einsum1 tiles 2,3 (reuse af) ----
        #pragma unroll
        for (int t = 2; t < 4; t++) {
            const uint4 ub = *(const uint4*)&feat_s[g * 1288 + ((t - 2) * 16 + cl) * 40 + q * 8];
            floatx4 dd = {0.f, 0.f, 0.f, 0.f};
            dd = __builtin_amdgcn_mfma_f32_16x16x32_bf16(af, __builtin_bit_cast(short8, ub), dd, 0, 0, 0);
            const int kk    = 8 * t + (cl >> 1);
            const int q2    = (2 * cl + (q >> 1)) & 3;
            const int chunk = (p ^ (kk & 15)) | (q2 << 4);
            unsigned* wp = (unsigned*)awf + kk * 256 + chunk * 4 + (q & 1) * 2;
            wp[0] = pack_trunc(dd[0], dd[1]);
            wp[1] = pack_trunc(dd[2], dd[3]);
        }
        __syncthreads();
    }

    // ---- einsum2: out[p,c] = sum_kappa wf[p,kappa] * V[kappa,c]; wave g -> c-tile g ----
    floatx4 acc0 = {0.f, 0.f, 0.f, 0.f};
    floatx4 acc1 = {0.f, 0.f, 0.f, 0.f};
    const unsigned short* vpg = vp + g * 512 + lane * 8;
    #pragma unroll 8
    for (int kk = 0; kk < 32; kk++) {
        const int chunk = ((lane & 15) ^ (kk & 15)) | (lane & 48);
        const uint4 uA = *(const uint4*)&awf[kk * 512 + chunk * 8];
        const uint4 uB = *(const uint4*)(vpg + (size_t)kk * 2048);
        if (kk & 1)
            acc1 = __builtin_amdgcn_mfma_f32_16x16x32_bf16(
                __builtin_bit_cast(short8, uA), __builtin_bit_cast(short8, uB), acc1, 0, 0, 0);
        else
            acc0 = __builtin_amdgcn_mfma_f32_16x16x32_bf16(
                __builtin_bit_cast(short8, uA), __builtin_bit_cast(short8, uB), acc0, 0, 0, 0);
    }
    const floatx4 acc = acc0 + acc1;

    // D: row = q*4+ri = p, col = cl = c within tile g
    #pragma unroll
    for (int ri = 0; ri < 4; ri++) {
        out[((size_t)(batch * MPTS + m0 + q * 4 + ri)) * NC + g * 16 + cl] = acc[ri];
    }
}

extern "C" void kernel_launch(void* const* d_in, const int* in_sizes, int n_in,
                              void* d_out, int out_size, void* d_ws, size_t ws_size,
                              hipStream_t stream) {
    const float* points   = (const float*)d_in[0];
    const float* features = (const float*)d_in[1];
    const float* outpts   = (const float*)d_in[2];
    const float* kpts     = (const float*)d_in[3];
    const float* kvals    = (const float*)d_in[4];
    const int*   nbr      = (const int*)d_in[5];
    float* out = (float*)d_out;

    unsigned short* vp     = (unsigned short*)d_ws;                   // 131072 B
    unsigned short* featbf = (unsigned short*)((char*)d_ws + 131072); // 8 MB

    vprep_kernel<<<32, 256, 0, stream>>>(kvals, vp);
    feat_cvt_kernel<<<2048, 256, 0, stream>>>(features, featbf);

    const int blocks = BATCH * (MPTS / MT);   // 4096
    kpconv_kernel<<<blocks, 256, 0, stream>>>(points, featbf, outpts, kpts, vp, nbr, out);
}

// Round 4
// 143.532 us; speedup vs baseline: 1.1413x; 1.1413x over previous
//
#include <hip/hip_runtime.h>

#define BATCH 4
#define NPTS 16384
#define MPTS 16384
#define NH 32
#define NK 15
#define NF 64
#define NC 64
#define MT 16

typedef short short8 __attribute__((ext_vector_type(8)));
typedef float floatx4 __attribute__((ext_vector_type(4)));

__device__ __forceinline__ unsigned short f2bf(float x) {
    unsigned int u = __builtin_bit_cast(unsigned int, x);
    u = u + 0x7FFFu + ((u >> 16) & 1u);   // RNE
    return (unsigned short)(u >> 16);
}

// pack two floats -> bf16x2 dword by truncation (1 v_perm)
__device__ __forceinline__ unsigned pack_trunc(float lo, float hi) {
    return __builtin_amdgcn_perm(__builtin_bit_cast(unsigned, hi),
                                 __builtin_bit_cast(unsigned, lo), 0x07060302u);
}

// ---------- fused prep: blocks [0,32) = V re-layout; [32, 2080) = feat fp32->bf16 ----------
__global__ void prep_kernel(const float* __restrict__ kv, const float* __restrict__ feat,
                            unsigned short* __restrict__ vp, unsigned short* __restrict__ featbf) {
    if (blockIdx.x < 32) {
        // kappa = f*16 + k (k padded to 16, zero for k==15). KF = 1024 -> 32 mfma steps.
        const int gid = blockIdx.x * 256 + threadIdx.x;        // 8192 threads
        const int lane = gid & 63;
        const int ct   = (gid >> 6) & 3;
        const int kk   = gid >> 8;                             // 0..31
        const int c    = ct * 16 + (lane & 15);
        const int kap0 = kk * 32 + (lane >> 4) * 8;
        unsigned int o[4];
        #pragma unroll
        for (int jj = 0; jj < 4; jj++) {
            unsigned short lo, hi;
            {
                const int kap = kap0 + jj * 2;
                const int f = kap >> 4, k = kap & 15;
                lo = (k < NK) ? f2bf(kv[((size_t)(k * NF + f)) * NC + c]) : (unsigned short)0;
            }
            {
                const int kap = kap0 + jj * 2 + 1;
                const int f = kap >> 4, k = kap & 15;
                hi = (k < NK) ? f2bf(kv[((size_t)(k * NF + f)) * NC + c]) : (unsigned short)0;
            }
            o[jj] = (unsigned)lo | ((unsigned)hi << 16);
        }
        *(uint4*)(vp + (size_t)gid * 8) = make_uint4(o[0], o[1], o[2], o[3]);
    } else {
        const int gid = (blockIdx.x - 32) * 256 + threadIdx.x; // 524288 threads x 8 elems
        const size_t base = (size_t)gid * 8;
        float4 a = *(const float4*)(feat + base);
        float4 b = *(const float4*)(feat + base + 4);
        uint4 o;
        o.x = (unsigned)f2bf(a.x) | ((unsigned)f2bf(a.y) << 16);
        o.y = (unsigned)f2bf(a.z) | ((unsigned)f2bf(a.w) << 16);
        o.z = (unsigned)f2bf(b.x) | ((unsigned)f2bf(b.y) << 16);
        o.w = (unsigned)f2bf(b.z) | ((unsigned)f2bf(b.w) << 16);
        *(uint4*)(featbf + base) = o;
    }
}

// ---------- main kernel ----------
__global__ __launch_bounds__(256, 5) void kpconv_kernel(
    const float* __restrict__ points,          // [B,N,3]
    const unsigned short* __restrict__ featbf, // [B,N,F] bf16 (ws)
    const float* __restrict__ outpts,          // [B,M,3]
    const float* __restrict__ kpts,            // [K,3]
    const unsigned short* __restrict__ vp,     // einsum2 B-frag-ordered V bf16 (ws)
    const int*   __restrict__ nbr,             // [B,M,H]
    float* __restrict__ out)                   // [B,M,C]
{
    // awf: wf in einsum2 A-frag order for ONE kappa-half: [kk 0..15][chunk(swizzled)][8]
    // During the prologue it is aliased as rel4[512] (float4).
    __shared__ __align__(16) unsigned short awf[16 * 512];   // 16384 B
    __shared__ unsigned short feat_s[4 * 1288];              // [wave][floc<32][h pad40] 10304 B
    __shared__ int   idx_s[512];                             //                          2048 B
    __shared__ float opt_s[48];
    __shared__ float kp_s[48];

    const int tid   = threadIdx.x;
    const int batch = blockIdx.x >> 10;
    const int m0    = (blockIdx.x & 1023) << 4;

    if (tid < 48) kp_s[tid] = (tid < 45) ? kpts[tid] : 1e9f;   // sentinel -> w=0 for k=15
    if (tid >= 64 && tid < 112)
        opt_s[tid - 64] = outpts[(size_t)(batch * MPTS + m0) * 3 + (tid - 64)];
    {
        const size_t nb = (size_t)(batch * MPTS + m0) * NH;
        idx_s[tid]       = nbr[nb + tid];
        idx_s[256 + tid] = nbr[nb + 256 + tid];
    }
    __syncthreads();   // B1: idx/opt/kp ready

    const int g    = tid >> 6;    // wave id; feat_s partition g is wave-private
    const int lane = tid & 63;
    const int cl   = lane & 15;
    const int q    = lane >> 4;
    const int sa   = cl;          // h-pair handled by this lane in staging
    const int sfc  = q;           // f-chunk of 8 shorts in staging

    const unsigned short* fbase = featbf + (size_t)(batch * NPTS) * NF;

    // ---- issue iter-0 gather immediately (consumed after 2 barriers of latency) ----
    uint4 pra, prb;
    {
        const int srow = g * 32 + sa * 2;                      // r=0, fh=0
        const int id0 = idx_s[srow], id1 = idx_s[srow + 1];
        pra = *(const uint4*)(fbase + (size_t)id0 * NF + sfc * 8);
        prb = *(const uint4*)(fbase + (size_t)id1 * NF + sfc * 8);
    }

    // ---- stage rel coords into awf alias ----
    float4* rel4 = (float4*)awf;
    #pragma unroll
    for (int rr = 0; rr < 2; rr++) {
        const int row = tid * 2 + rr;            // 0..511 = p*32 + h
        const int id  = idx_s[row];
        const int pm  = row >> 5;
        const float* pp = points + ((size_t)(batch * NPTS) + id) * 3;
        rel4[row] = make_float4(pp[0] - opt_s[pm * 3 + 0],
                                pp[1] - opt_s[pm * 3 + 1],
                                pp[2] - opt_s[pm * 3 + 2], 0.f);
    }
    __syncthreads();   // B2: rel ready

    // ---- compute all w A-frags for this wave's 4 points (held in registers) ----
    short8 af[4];
    {
        const float kx = kp_s[cl * 3 + 0];
        const float ky = kp_s[cl * 3 + 1];
        const float kz = kp_s[cl * 3 + 2];
        #pragma unroll
        for (int rp = 0; rp < 4; rp++) {
            const int p = rp * 4 + g;
            float wv[8];
            #pragma unroll
            for (int j = 0; j < 8; j++) {
                const float4 rr = rel4[p * 32 + q * 8 + j];    // broadcast across cl
                const float dx = rr.x - kx, dy = rr.y - ky, dz = rr.z - kz;
                const float d = sqrtf(dx * dx + dy * dy + dz * dz);
                wv[j] = fmaxf(1.f - d, 0.f);                   // EXTENT = 1.0
            }
            uint4 ua;
            ua.x = pack_trunc(wv[0], wv[1]);
            ua.y = pack_trunc(wv[2], wv[3]);
            ua.z = pack_trunc(wv[4], wv[5]);
            ua.w = pack_trunc(wv[6], wv[7]);
            af[rp] = __builtin_bit_cast(short8, ua);
        }
    }
    __syncthreads();   // B3: rel4 dead -> awf free for einsum1 output

    floatx4 acc0 = {0.f, 0.f, 0.f, 0.f};
    floatx4 acc1 = {0.f, 0.f, 0.f, 0.f};
    const unsigned short* vpg = vp + g * 512 + lane * 8;
    unsigned short* dp = &feat_s[g * 1288 + (sfc * 8) * 40 + sa * 2];

    #pragma unroll
    for (int it = 0; it < 8; it++) {
        const int r  = it & 3;      // round (4 points each)
        const int p  = r * 4 + g;

        // (a) stage this iter's f-half from prefetched regs (wave-private LDS, no barrier)
        *(unsigned*)(dp + 0 * 40) = __builtin_amdgcn_perm(prb.x, pra.x, 0x05040100u);
        *(unsigned*)(dp + 1 * 40) = __builtin_amdgcn_perm(prb.x, pra.x, 0x07060302u);
        *(unsigned*)(dp + 2 * 40) = __builtin_amdgcn_perm(prb.y, pra.y, 0x05040100u);
        *(unsigned*)(dp + 3 * 40) = __builtin_amdgcn_perm(prb.y, pra.y, 0x07060302u);
        *(unsigned*)(dp + 4 * 40) = __builtin_amdgcn_perm(prb.z, pra.z, 0x05040100u);
        *(unsigned*)(dp + 5 * 40) = __builtin_amdgcn_perm(prb.z, pra.z, 0x07060302u);
        *(unsigned*)(dp + 6 * 40) = __builtin_amdgcn_perm(prb.w, pra.w, 0x05040100u);
        *(unsigned*)(dp + 7 * 40) = __builtin_amdgcn_perm(prb.w, pra.w, 0x07060302u);

        // (b) prefetch next iter's gathers
        if (it < 7) {
            const int nit = it + 1;
            const int nfh = nit >> 2, nr = nit & 3;
            const int srow = (nr * 4 + g) * 32 + sa * 2;
            const int id0 = idx_s[srow], id1 = idx_s[srow + 1];
            pra = *(const uint4*)(fbase + (size_t)id0 * NF + nfh * 32 + sfc * 8);
            prb = *(const uint4*)(fbase + (size_t)id1 * NF + nfh * 32 + sfc * 8);
        }

        // (c) einsum1: 2 f-tiles of 16 for point p
        #pragma unroll
        for (int t = 0; t < 2; t++) {
            const uint4 ub = *(const uint4*)&feat_s[g * 1288 + (t * 16 + cl) * 40 + q * 8];
            floatx4 dd = {0.f, 0.f, 0.f, 0.f};
            dd = __builtin_amdgcn_mfma_f32_16x16x32_bf16(af[r], __builtin_bit_cast(short8, ub), dd, 0, 0, 0);
            const int kk    = 8 * t + (cl >> 1);               // local kappa-chunk 0..15
            const int q2    = (2 * cl + (q >> 1)) & 3;
            const int chunk = (p ^ kk) | (q2 << 4);
            unsigned* wp = (unsigned*)awf + kk * 256 + chunk * 4 + (q & 1) * 2;
            wp[0] = pack_trunc(dd[0], dd[1]);
            wp[1] = pack_trunc(dd[2], dd[3]);
        }

        // (d) at f-half boundary: einsum2 partial over this kappa-half
        if (it == 3) {
            __syncthreads();   // B4: awf (fh=0) complete
            #pragma unroll 4
            for (int kk = 0; kk < 16; kk++) {
                const int chunk = (cl ^ kk) | (lane & 48);
                const uint4 uA = *(const uint4*)&awf[kk * 512 + chunk * 8];
                const uint4 uB = *(const uint4*)(vpg + (size_t)kk * 2048);
                if (kk & 1)
                    acc1 = __builtin_amdgcn_mfma_f32_16x16x32_bf16(
                        __builtin_bit_cast(short8, uA), __builtin_bit_cast(short8, uB), acc1, 0, 0, 0);
                else
                    acc0 = __builtin_amdgcn_mfma_f32_16x16x32_bf16(
                        __builtin_bit_cast(short8, uA), __builtin_bit_cast(short8, uB), acc0, 0, 0, 0);
            }
            __syncthreads();   // B5: einsum2 reads done -> awf reusable for fh=1
        }
    }

    __syncthreads();   // B6: awf (fh=1) complete
    #pragma unroll 4
    for (int kk = 0; kk < 16; kk++) {
        const int chunk = (cl ^ kk) | (lane & 48);
        const uint4 uA = *(const uint4*)&awf[kk * 512 + chunk * 8];
        const uint4 uB = *(const uint4*)(vpg + (size_t)(16 + kk) * 2048);
        if (kk & 1)
            acc1 = __builtin_amdgcn_mfma_f32_16x16x32_bf16(
                __builtin_bit_cast(short8, uA), __builtin_bit_cast(short8, uB), acc1, 0, 0, 0);
        else
            acc0 = __builtin_amdgcn_mfma_f32_16x16x32_bf16(
                __builtin_bit_cast(short8, uA), __builtin_bit_cast(short8, uB), acc0, 0, 0, 0);
    }
    const floatx4 acc = acc0 + acc1;

    // D: row = q*4+ri = point, col = cl = c within c-tile g
    #pragma unroll
    for (int ri = 0; ri < 4; ri++) {
        out[((size_t)(batch * MPTS + m0 + q * 4 + ri)) * NC + g * 16 + cl] = acc[ri];
    }
}

extern "C" void kernel_launch(void* const* d_in, const int* in_sizes, int n_in,
                              void* d_out, int out_size, void* d_ws, size_t ws_size,
                              hipStream_t stream) {
    const float* points   = (const float*)d_in[0];
    const float* features = (const float*)d_in[1];
    const float* outpts   = (const float*)d_in[2];
    const float* kpts     = (const float*)d_in[3];
    const float* kvals    = (const float*)d_in[4];
    const int*   nbr      = (const int*)d_in[5];
    float* out = (float*)d_out;

    unsigned short* vp     = (unsigned short*)d_ws;                   // 131072 B
    unsigned short* featbf = (unsigned short*)((char*)d_ws + 131072); // 8 MB

    prep_kernel<<<2080, 256, 0, stream>>>(kvals, features, vp, featbf);

    const int blocks = BATCH * (MPTS / MT);   // 4096
    kpconv_kernel<<<blocks, 256, 0, stream>>>(points, featbf, outpts, kpts, vp, nbr, out);
}